// Round 2
// baseline (1223.532 us; speedup 1.0000x reference)
//
#include <hip/hip_runtime.h>
#include <hip/hip_bf16.h>

// Problem constants (HierarchicalMambaBlock: B=2,T=1024,DIM=512,EXPAND=2,
// D_STATE=16, CONV_K=4, NUM_SCALES=3 -> D_INNER=1024, DT_RANK=64)
// ALL tensors are float32 (per reference dtypes).
#define BATCH   2
#define SEQ     1024
#define DIMSZ   512
#define DINNER  1024
#define DTRANK  64
#define DSTATE  16

__device__ __forceinline__ float sigmoidf_(float x) { return 1.f / (1.f + __expf(-x)); }
__device__ __forceinline__ float siluf_(float x) { return x * sigmoidf_(x); }

// ---------------------------------------------------------------------------
// Tiled GEMM: C[M,N] = act(A[M,K] @ W[N,K]^T + bias) (+ addsrc)
// All f32. ACT: 0=none 1=silu 2=sigmoid 3=softplus
// Requires: K % 16 == 0, lda % 4 == 0, ldc == N for addsrc indexing.
// ---------------------------------------------------------------------------
template <int ACT, bool HAS_BIAS, bool ADD_SRC>
__global__ __launch_bounds__(256) void gemm_kernel(
    const float* __restrict__ A, int lda,
    const float* __restrict__ W,
    const float* __restrict__ bias,
    const float* __restrict__ addsrc,
    float* __restrict__ C, int ldc,
    int M, int N, int K)
{
    const int BM = 64, BN = 64, BK = 16;
    __shared__ __align__(16) float As[BK][BM + 4];
    __shared__ __align__(16) float Bs[BK][BN + 4];

    const int m0 = blockIdx.x * BM;
    const int n0 = blockIdx.y * BN;
    const int tid = threadIdx.x;
    const int ty = tid >> 4;        // 0..15
    const int tx = tid & 15;        // 0..15
    const int arow = tid >> 2;      // 0..63
    const int acol = (tid & 3) * 4; // 0,4,8,12

    float acc[4][4] = {};

    for (int k0 = 0; k0 < K; k0 += BK) {
        // A tile -> As[k][m] (transposed)
        {
            int m = m0 + arow;
            float4 v = make_float4(0.f, 0.f, 0.f, 0.f);
            if (m < M)
                v = *reinterpret_cast<const float4*>(A + (size_t)m * lda + (k0 + acol));
            As[acol + 0][arow] = v.x; As[acol + 1][arow] = v.y;
            As[acol + 2][arow] = v.z; As[acol + 3][arow] = v.w;
        }
        // W tile -> Bs[k][n]
        {
            int n = n0 + arow;
            float4 v = make_float4(0.f, 0.f, 0.f, 0.f);
            if (n < N)
                v = *reinterpret_cast<const float4*>(W + (size_t)n * K + (k0 + acol));
            Bs[acol + 0][arow] = v.x; Bs[acol + 1][arow] = v.y;
            Bs[acol + 2][arow] = v.z; Bs[acol + 3][arow] = v.w;
        }
        __syncthreads();

#pragma unroll
        for (int k = 0; k < BK; k++) {
            const float4 av = *reinterpret_cast<const float4*>(&As[k][ty * 4]);
            const float4 bv = *reinterpret_cast<const float4*>(&Bs[k][tx * 4]);
            float a[4] = { av.x, av.y, av.z, av.w };
            float b[4] = { bv.x, bv.y, bv.z, bv.w };
#pragma unroll
            for (int i = 0; i < 4; i++)
#pragma unroll
                for (int j = 0; j < 4; j++)
                    acc[i][j] = fmaf(a[i], b[j], acc[i][j]);
        }
        __syncthreads();
    }

#pragma unroll
    for (int i = 0; i < 4; i++) {
        int m = m0 + ty * 4 + i;
        if (m >= M) continue;
#pragma unroll
        for (int j = 0; j < 4; j++) {
            int n = n0 + tx * 4 + j;
            if (n >= N) continue;
            float v = acc[i][j];
            if (HAS_BIAS) v += bias[n];
            if (ACT == 1) v = siluf_(v);
            else if (ACT == 2) v = sigmoidf_(v);
            else if (ACT == 3) v = (v > 20.f) ? v : __logf(1.f + __expf(v));
            if (ADD_SRC) v += addsrc[(size_t)m * ldc + n];
            C[(size_t)m * ldc + n] = v;
        }
    }
}

// ---------------------------------------------------------------------------
// Downsample: out[b,t,c] = mean_{k<stride} X[b, t*stride+k, c]   (X ld = ldx)
// ---------------------------------------------------------------------------
__global__ void downsample_kernel(const float* __restrict__ X, int ldx,
                                  int Tout, int stride, float* __restrict__ out)
{
    int idx = blockIdx.x * blockDim.x + threadIdx.x;
    int total = BATCH * Tout * DINNER;
    if (idx >= total) return;
    int c = idx & (DINNER - 1);
    int row = idx >> 10;          // b*Tout + t
    int b = row / Tout;
    int t = row - b * Tout;
    const float* base = X + ((size_t)(b * Tout * stride) + (size_t)t * stride) * ldx + c;
    float s = 0.f;
    for (int k = 0; k < stride; k++) s += base[(size_t)k * ldx];
    out[idx] = s * (1.f / (float)stride);
}

// ---------------------------------------------------------------------------
// Depthwise causal conv (K=4) + bias + SiLU. X ld = ldx; out ld = 1024.
// ---------------------------------------------------------------------------
__global__ void conv_silu_kernel(const float* __restrict__ X, int ldx, int Ts,
                                 const float* __restrict__ cw,  // [1024*4] this scale
                                 const float* __restrict__ cb,  // [1024]
                                 float* __restrict__ out)
{
    int idx = blockIdx.x * blockDim.x + threadIdx.x;
    int total = BATCH * Ts * DINNER;
    if (idx >= total) return;
    int c = idx & (DINNER - 1);
    int row = idx >> 10;
    int b = row / Ts;
    int t = row - b * Ts;
    float acc = cb[c];
    const float* base = X + (size_t)(b * Ts) * ldx;
#pragma unroll
    for (int k = 0; k < 4; k++) {
        int tt = t - 3 + k;
        if (tt >= 0) acc = fmaf(cw[c * 4 + k], base[(size_t)tt * ldx + c], acc);
    }
    out[idx] = siluf_(acc);
}

// ---------------------------------------------------------------------------
// Selective scan, all 3 scales in one launch. Thread = (scale,b,d); 16 states
// in registers. Matches reference log-space scan incl. 1e-38 clamps:
//   h_t = max(exp(dt*A),1e-38) * h_{t-1} + max(dt*B_t*x_t, 1e-38)
//   y_t = sum_j C_t[j]*h[j] + D_p*x_t
// dt already softplus'ed (fused into dtproj epilogue).
// ---------------------------------------------------------------------------
__global__ __launch_bounds__(256) void scan_kernel(
    const float* __restrict__ dt0, const float* __restrict__ xc0,
    const float* __restrict__ pj0, float* __restrict__ y0,
    const float* __restrict__ dt1, const float* __restrict__ xc1,
    const float* __restrict__ pj1, float* __restrict__ y1,
    const float* __restrict__ dt2, const float* __restrict__ xc2,
    const float* __restrict__ pj2, float* __restrict__ y2,
    const float* __restrict__ A_log, const float* __restrict__ D_p)
{
    int blk = blockIdx.x;
    int s = blk >> 3;
    int r = blk & 7;
    int b = r >> 2;
    int chunk = r & 3;
    const float *dt, *xc, *pj; float* y; int Ts;
    if (s == 0) { dt = dt0; xc = xc0; pj = pj0; y = y0; Ts = 1024; }
    else if (s == 1) { dt = dt1; xc = xc1; pj = pj1; y = y1; Ts = 512; }
    else { dt = dt2; xc = xc2; pj = pj2; y = y2; Ts = 256; }

    const int d = chunk * 256 + threadIdx.x;
    float Acoef[16], h[16];
#pragma unroll
    for (int j = 0; j < 16; j++) {
        Acoef[j] = -__expf(A_log[((size_t)(s * DINNER + d)) * 16 + j]);
        h[j] = 0.f;
    }
    const float Dp = D_p[s * DINNER + d];

    __shared__ float bc[128][32];  // B (cols 0..15) and C (cols 16..31) per t
    const size_t rowbase = (size_t)b * Ts;

    for (int t0 = 0; t0 < Ts; t0 += 128) {
        __syncthreads();
        for (int u = threadIdx.x; u < 128 * 32; u += 256) {
            int i = u >> 5, j = u & 31;
            bc[i][j] = pj[(rowbase + t0 + i) * 96 + 64 + j];
        }
        __syncthreads();
        for (int i = 0; i < 128; i++) {
            size_t t = rowbase + t0 + i;
            float dtv = dt[t * DINNER + d];
            float xv  = xc[t * DINNER + d];
            float accy = 0.f;
#pragma unroll
            for (int j = 0; j < 16; j++) {
                float dA = fmaxf(__expf(dtv * Acoef[j]), 1e-38f);
                float dbx = fmaxf(dtv * bc[i][j] * xv, 1e-38f);
                h[j] = fmaf(dA, h[j], dbx);
                accy = fmaf(bc[i][16 + j], h[j], accy);
            }
            y[t * DINNER + d] = accy + Dp * xv;
        }
    }
}

// ---------------------------------------------------------------------------
// fused = softmax(sw)-weighted sum of upsampled y_s; ctx = mean of them.
// ---------------------------------------------------------------------------
__global__ void fuse_kernel(const float* __restrict__ y0, const float* __restrict__ y1,
                            const float* __restrict__ y2, const float* __restrict__ sw,
                            float* __restrict__ fused, float* __restrict__ ctx)
{
    int idx = blockIdx.x * blockDim.x + threadIdx.x;
    if (idx >= BATCH * SEQ * DINNER) return;
    int d = idx & (DINNER - 1);
    int t = (idx >> 10) & (SEQ - 1);
    int b = idx >> 20;
    float v0 = y0[idx];
    float v1 = y1[((size_t)(b * 512) + (t >> 1)) * DINNER + d];
    float v2 = y2[((size_t)(b * 256) + (t >> 2)) * DINNER + d];
    float s0 = sw[0], s1 = sw[1], s2 = sw[2];
    float mx = fmaxf(s0, fmaxf(s1, s2));
    float e0 = __expf(s0 - mx), e1 = __expf(s1 - mx), e2 = __expf(s2 - mx);
    float inv = 1.f / (e0 + e1 + e2);
    fused[idx] = (e0 * v0 + e1 * v1 + e2 * v2) * inv;
    ctx[idx] = (v0 + v1 + v2) * (1.f / 3.f);
}

// fused *= cg * silu(gate)   (gate = xz col 1024..2047)
__global__ void gate_mul_kernel(float* __restrict__ fused, const float* __restrict__ cg,
                                const float* __restrict__ xz)
{
    int idx = blockIdx.x * blockDim.x + threadIdx.x;
    if (idx >= BATCH * SEQ * DINNER) return;
    int token = idx >> 10;
    int d = idx & (DINNER - 1);
    float g = xz[(size_t)token * 2048 + 1024 + d];
    fused[idx] = fused[idx] * cg[idx] * siluf_(g);
}

// LayerNorm over DIM=512 per token; f32 out.
__global__ __launch_bounds__(256) void ln_kernel(
    const float* __restrict__ yin, const float* __restrict__ gamma,
    const float* __restrict__ beta, float* __restrict__ out)
{
    int token = blockIdx.x;
    int tid = threadIdx.x;
    const float* row = yin + (size_t)token * DIMSZ;
    float v0 = row[tid], v1 = row[tid + 256];
    __shared__ float s1[256], s2[256];
    s1[tid] = v0 + v1;
    s2[tid] = v0 * v0 + v1 * v1;
    __syncthreads();
    for (int off = 128; off > 0; off >>= 1) {
        if (tid < off) { s1[tid] += s1[tid + off]; s2[tid] += s2[tid + off]; }
        __syncthreads();
    }
    float mu = s1[0] * (1.f / 512.f);
    float var = s2[0] * (1.f / 512.f) - mu * mu;
    float rstd = rsqrtf(var + 1e-5f);
    float* orow = out + (size_t)token * DIMSZ;
    orow[tid]       = (v0 - mu) * rstd * gamma[tid]       + beta[tid];
    orow[tid + 256] = (v1 - mu) * rstd * gamma[tid + 256] + beta[tid + 256];
}

// ---------------------------------------------------------------------------
extern "C" void kernel_launch(void* const* d_in, const int* in_sizes, int n_in,
                              void* d_out, int out_size, void* d_ws, size_t ws_size,
                              hipStream_t stream)
{
    const float* x         = (const float*)d_in[0];
    const float* in_proj_w = (const float*)d_in[1];
    const float* conv_w    = (const float*)d_in[2];
    const float* conv_b    = (const float*)d_in[3];
    const float* xproj_w   = (const float*)d_in[4];
    const float* dtproj_w  = (const float*)d_in[5];
    const float* dtproj_b  = (const float*)d_in[6];
    const float* A_log     = (const float*)d_in[7];
    const float* D_p       = (const float*)d_in[8];
    const float* scale_w   = (const float*)d_in[9];
    const float* cg_w1     = (const float*)d_in[10];
    const float* cg_w2     = (const float*)d_in[11];
    const float* out_pw    = (const float*)d_in[12];
    const float* ln_gamma  = (const float*)d_in[13];
    const float* ln_beta   = (const float*)d_in[14];
    float* out = (float*)d_out;

    float* ws = (float*)d_ws;
    // f32 workspace layout (element offsets); later stages overlay dead buffers
    float* xz    = ws;                       // 2048 x 2048
    float* xs1   = xz    + 4194304;          // 1024 x 1024
    float* xs2   = xs1   + 1048576;          // 512  x 1024
    float* xc0   = xs2   + 524288;           // 2048 x 1024
    float* xc1   = xc0   + 2097152;          // 1024 x 1024
    float* xc2   = xc1   + 1048576;          // 512  x 1024
    float* pj0   = xc2   + 524288;           // 2048 x 96
    float* pj1   = pj0   + 196608;           // 1024 x 96
    float* pj2   = pj1   + 98304;            // 512  x 96
    float* dt0   = pj2   + 49152;            // 2048 x 1024 (softplus'ed)
    float* dt1   = dt0   + 2097152;          // 1024 x 1024
    float* dt2   = dt1   + 1048576;          // 512  x 1024
    float* y0    = dt2   + 524288;           // 2048 x 1024
    float* y1    = y0    + 2097152;          // 1024 x 1024
    float* y2    = y1    + 1048576;          // 512  x 1024
    // overlays (dead after scan):
    float* fused = dt0;                      // 2048 x 1024
    float* ctx   = xc0;                      // 2048 x 1024 (then reused as cg out)
    float* h1cg  = dt1;                      // 2048 x 512
    float* outpre= xc1;                      // 2048 x 512
    // total ws: (y2 end) = 17,121,280 floats = 68.5 MB

    const int M0 = BATCH * SEQ;   // 2048 tokens
    const int M1 = BATCH * 512;
    const int M2 = BATCH * 256;

    // 1) in_proj: xz = x @ in_proj_w^T   (M=2048,N=2048,K=512)
    gemm_kernel<0, false, false><<<dim3(M0 / 64, 2048 / 64), 256, 0, stream>>>(
        x, DIMSZ, in_proj_w, nullptr, nullptr, xz, 2048, M0, 2048, DIMSZ);

    // 2) downsample x_in (xz cols 0..1023, ld 2048)
    downsample_kernel<<<(BATCH * 512 * DINNER) / 256, 256, 0, stream>>>(xz, 2048, 512, 2, xs1);
    downsample_kernel<<<(BATCH * 256 * DINNER) / 256, 256, 0, stream>>>(xz, 2048, 256, 4, xs2);

    // 3) conv + SiLU per scale
    conv_silu_kernel<<<(BATCH * 1024 * DINNER) / 256, 256, 0, stream>>>(
        xz, 2048, 1024, conv_w + 0 * 4096, conv_b + 0 * DINNER, xc0);
    conv_silu_kernel<<<(BATCH * 512 * DINNER) / 256, 256, 0, stream>>>(
        xs1, 1024, 512, conv_w + 1 * 4096, conv_b + 1 * DINNER, xc1);
    conv_silu_kernel<<<(BATCH * 256 * DINNER) / 256, 256, 0, stream>>>(
        xs2, 1024, 256, conv_w + 2 * 4096, conv_b + 2 * DINNER, xc2);

    // 4) xproj per scale: proj = xc @ xproj_w[s]^T  (N=96,K=1024)
    gemm_kernel<0, false, false><<<dim3(M0 / 64, 2), 256, 0, stream>>>(
        xc0, DINNER, xproj_w + 0 * 96 * DINNER, nullptr, nullptr, pj0, 96, M0, 96, DINNER);
    gemm_kernel<0, false, false><<<dim3(M1 / 64, 2), 256, 0, stream>>>(
        xc1, DINNER, xproj_w + 1 * 96 * DINNER, nullptr, nullptr, pj1, 96, M1, 96, DINNER);
    gemm_kernel<0, false, false><<<dim3(M2 / 64, 2), 256, 0, stream>>>(
        xc2, DINNER, xproj_w + 2 * 96 * DINNER, nullptr, nullptr, pj2, 96, M2, 96, DINNER);

    // 5) dtproj per scale: dt = softplus(dt_raw @ dtproj_w[s]^T + b)  (N=1024,K=64)
    gemm_kernel<3, true, false><<<dim3(M0 / 64, 16), 256, 0, stream>>>(
        pj0, 96, dtproj_w + 0 * DINNER * DTRANK, dtproj_b + 0 * DINNER, nullptr,
        dt0, DINNER, M0, DINNER, DTRANK);
    gemm_kernel<3, true, false><<<dim3(M1 / 64, 16), 256, 0, stream>>>(
        pj1, 96, dtproj_w + 1 * DINNER * DTRANK, dtproj_b + 1 * DINNER, nullptr,
        dt1, DINNER, M1, DINNER, DTRANK);
    gemm_kernel<3, true, false><<<dim3(M2 / 64, 16), 256, 0, stream>>>(
        pj2, 96, dtproj_w + 2 * DINNER * DTRANK, dtproj_b + 2 * DINNER, nullptr,
        dt2, DINNER, M2, DINNER, DTRANK);

    // 6) selective scan, all scales
    scan_kernel<<<24, 256, 0, stream>>>(dt0, xc0, pj0, y0,
                                        dt1, xc1, pj1, y1,
                                        dt2, xc2, pj2, y2, A_log, D_p);

    // 7) fuse + ctx  (fused overlays dt0, ctx overlays xc0 — both dead now)
    fuse_kernel<<<(BATCH * SEQ * DINNER) / 256, 256, 0, stream>>>(y0, y1, y2, scale_w, fused, ctx);

    // 8) cg1: h1 = silu(ctx @ cg_w1^T)  (N=512,K=1024)
    gemm_kernel<1, false, false><<<dim3(M0 / 64, 8), 256, 0, stream>>>(
        ctx, DINNER, cg_w1, nullptr, nullptr, h1cg, 512, M0, 512, DINNER);

    // 9) cg2: cg = sigmoid(h1 @ cg_w2^T)  (N=1024,K=512) -> overwrite ctx
    gemm_kernel<2, false, false><<<dim3(M0 / 64, 16), 256, 0, stream>>>(
        h1cg, 512, cg_w2, nullptr, nullptr, ctx, DINNER, M0, DINNER, 512);

    // 10) fused *= cg * silu(gate)
    gate_mul_kernel<<<(BATCH * SEQ * DINNER) / 256, 256, 0, stream>>>(fused, ctx, xz);

    // 11) out_proj + residual: outpre = fused @ out_pw^T + x  (N=512,K=1024)
    gemm_kernel<0, false, true><<<dim3(M0 / 64, 8), 256, 0, stream>>>(
        fused, DINNER, out_pw, nullptr, x, outpre, DIMSZ, M0, DIMSZ, DINNER);

    // 12) LayerNorm -> f32 out
    ln_kernel<<<M0, 256, 0, stream>>>(outpre, ln_gamma, ln_beta, out);
}

// Round 3
// 645.773 us; speedup vs baseline: 1.8947x; 1.8947x over previous
//
#include <hip/hip_runtime.h>
#include <hip/hip_bf16.h>

// Problem constants (HierarchicalMambaBlock: B=2,T=1024,DIM=512,EXPAND=2,
// D_STATE=16, CONV_K=4, NUM_SCALES=3 -> D_INNER=1024, DT_RANK=64)
// ALL tensors are float32 (per reference dtypes).
#define BATCH   2
#define SEQ     1024
#define DIMSZ   512
#define DINNER  1024
#define DTRANK  64
#define DSTATE  16
#define CHUNK   32   // scan chunk length (time steps per block)

__device__ __forceinline__ float sigmoidf_(float x) { return 1.f / (1.f + __expf(-x)); }
__device__ __forceinline__ float siluf_(float x) { return x * sigmoidf_(x); }

// ---------------------------------------------------------------------------
// Tiled GEMM: C[M,N] = act(A[M,K] @ W[N,K]^T + bias) (+ addsrc)
// All f32. ACT: 0=none 1=silu 2=sigmoid 3=softplus
// Requires: K % 16 == 0, lda % 4 == 0, ldc == N for addsrc indexing.
// ---------------------------------------------------------------------------
template <int ACT, bool HAS_BIAS, bool ADD_SRC>
__global__ __launch_bounds__(256) void gemm_kernel(
    const float* __restrict__ A, int lda,
    const float* __restrict__ W,
    const float* __restrict__ bias,
    const float* __restrict__ addsrc,
    float* __restrict__ C, int ldc,
    int M, int N, int K)
{
    const int BM = 64, BN = 64, BK = 16;
    __shared__ __align__(16) float As[BK][BM + 4];
    __shared__ __align__(16) float Bs[BK][BN + 4];

    const int m0 = blockIdx.x * BM;
    const int n0 = blockIdx.y * BN;
    const int tid = threadIdx.x;
    const int ty = tid >> 4;        // 0..15
    const int tx = tid & 15;        // 0..15
    const int arow = tid >> 2;      // 0..63
    const int acol = (tid & 3) * 4; // 0,4,8,12

    float acc[4][4] = {};

    for (int k0 = 0; k0 < K; k0 += BK) {
        {
            int m = m0 + arow;
            float4 v = make_float4(0.f, 0.f, 0.f, 0.f);
            if (m < M)
                v = *reinterpret_cast<const float4*>(A + (size_t)m * lda + (k0 + acol));
            As[acol + 0][arow] = v.x; As[acol + 1][arow] = v.y;
            As[acol + 2][arow] = v.z; As[acol + 3][arow] = v.w;
        }
        {
            int n = n0 + arow;
            float4 v = make_float4(0.f, 0.f, 0.f, 0.f);
            if (n < N)
                v = *reinterpret_cast<const float4*>(W + (size_t)n * K + (k0 + acol));
            Bs[acol + 0][arow] = v.x; Bs[acol + 1][arow] = v.y;
            Bs[acol + 2][arow] = v.z; Bs[acol + 3][arow] = v.w;
        }
        __syncthreads();

#pragma unroll
        for (int k = 0; k < BK; k++) {
            const float4 av = *reinterpret_cast<const float4*>(&As[k][ty * 4]);
            const float4 bv = *reinterpret_cast<const float4*>(&Bs[k][tx * 4]);
            float a[4] = { av.x, av.y, av.z, av.w };
            float b[4] = { bv.x, bv.y, bv.z, bv.w };
#pragma unroll
            for (int i = 0; i < 4; i++)
#pragma unroll
                for (int j = 0; j < 4; j++)
                    acc[i][j] = fmaf(a[i], b[j], acc[i][j]);
        }
        __syncthreads();
    }

#pragma unroll
    for (int i = 0; i < 4; i++) {
        int m = m0 + ty * 4 + i;
        if (m >= M) continue;
#pragma unroll
        for (int j = 0; j < 4; j++) {
            int n = n0 + tx * 4 + j;
            if (n >= N) continue;
            float v = acc[i][j];
            if (HAS_BIAS) v += bias[n];
            if (ACT == 1) v = siluf_(v);
            else if (ACT == 2) v = sigmoidf_(v);
            else if (ACT == 3) v = (v > 20.f) ? v : __logf(1.f + __expf(v));
            if (ADD_SRC) v += addsrc[(size_t)m * ldc + n];
            C[(size_t)m * ldc + n] = v;
        }
    }
}

// ---------------------------------------------------------------------------
__global__ void downsample_kernel(const float* __restrict__ X, int ldx,
                                  int Tout, int stride, float* __restrict__ out)
{
    int idx = blockIdx.x * blockDim.x + threadIdx.x;
    int total = BATCH * Tout * DINNER;
    if (idx >= total) return;
    int c = idx & (DINNER - 1);
    int row = idx >> 10;
    int b = row / Tout;
    int t = row - b * Tout;
    const float* base = X + ((size_t)(b * Tout * stride) + (size_t)t * stride) * ldx + c;
    float s = 0.f;
    for (int k = 0; k < stride; k++) s += base[(size_t)k * ldx];
    out[idx] = s * (1.f / (float)stride);
}

// ---------------------------------------------------------------------------
__global__ void conv_silu_kernel(const float* __restrict__ X, int ldx, int Ts,
                                 const float* __restrict__ cw,
                                 const float* __restrict__ cb,
                                 float* __restrict__ out)
{
    int idx = blockIdx.x * blockDim.x + threadIdx.x;
    int total = BATCH * Ts * DINNER;
    if (idx >= total) return;
    int c = idx & (DINNER - 1);
    int row = idx >> 10;
    int b = row / Ts;
    int t = row - b * Ts;
    float acc = cb[c];
    const float* base = X + (size_t)(b * Ts) * ldx;
#pragma unroll
    for (int k = 0; k < 4; k++) {
        int tt = t - 3 + k;
        if (tt >= 0) acc = fmaf(cw[c * 4 + k], base[(size_t)tt * ldx + c], acc);
    }
    out[idx] = siluf_(acc);
}

// ---------------------------------------------------------------------------
// Chunked selective scan. Linear recurrence h_t = a_t h_{t-1} + b_t with
//   a_t = max(exp(dt*A),1e-38), b_t = max(dt*B_t*x_t,1e-38)
// Pass 1: per (scale,b,chunk,dquad) block, scan CHUNK steps from h=0, store
//         per-chunk prod(a) and final h  (layout [s][b][chunk][j][d], d fastest)
// Pass 2: rebuild carry-in from predecessor chunk states, re-scan, write y.
//
// Block decode (448 blocks): scale0=256, scale1=128, scale2=64 blocks.
//   nchunk = 32>>s; dquad = local&3; chunk = (local>>2)&(nchunk-1); b = local>>(7-s)
// chunkstate scale offsets (floats): s0=0, s1=1048576, s2=1572864 (total 1835008)
// ---------------------------------------------------------------------------
__device__ __forceinline__ void scan_decode(int blk, int& s, int& nchunk, int& Ts,
                                            int& dquad, int& chunk, int& b, size_t& soff)
{
    int local;
    if (blk < 256)      { s = 0; local = blk;       soff = 0; }
    else if (blk < 384) { s = 1; local = blk - 256; soff = 1048576; }
    else                { s = 2; local = blk - 384; soff = 1572864; }
    nchunk = 32 >> s;
    Ts = 1024 >> s;
    dquad = local & 3;
    chunk = (local >> 2) & (nchunk - 1);
    b = local >> (7 - s);
}

__global__ __launch_bounds__(256) void scan_pass1(
    const float* __restrict__ dt0, const float* __restrict__ xc0, const float* __restrict__ pj0,
    const float* __restrict__ dt1, const float* __restrict__ xc1, const float* __restrict__ pj1,
    const float* __restrict__ dt2, const float* __restrict__ xc2, const float* __restrict__ pj2,
    const float* __restrict__ A_log,
    float* __restrict__ prodA_buf, float* __restrict__ h_buf)
{
    int s, nchunk, Ts, dquad, chunk, b; size_t soff;
    scan_decode(blockIdx.x, s, nchunk, Ts, dquad, chunk, b, soff);
    const float* dt = (s == 0) ? dt0 : (s == 1) ? dt1 : dt2;
    const float* xc = (s == 0) ? xc0 : (s == 1) ? xc1 : xc2;
    const float* pj = (s == 0) ? pj0 : (s == 1) ? pj1 : pj2;

    const int d = dquad * 256 + threadIdx.x;
    const size_t rowbase = (size_t)b * Ts;
    const int t0 = chunk * CHUNK;

    float Acoef[16], h[16], p[16];
#pragma unroll
    for (int j = 0; j < 16; j++) {
        Acoef[j] = -__expf(A_log[((size_t)(s * DINNER + d)) * 16 + j]);
        h[j] = 0.f; p[j] = 1.f;
    }

    __shared__ float bcB[CHUNK][16];
    for (int u = threadIdx.x; u < CHUNK * 16; u += 256) {
        int i = u >> 4, jj = u & 15;
        bcB[i][jj] = pj[(rowbase + t0 + i) * 96 + 64 + jj];
    }
    __syncthreads();

    for (int i = 0; i < CHUNK; i++) {
        size_t t = rowbase + t0 + i;
        float dtv = dt[t * DINNER + d];
        float xv  = xc[t * DINNER + d];
#pragma unroll
        for (int j = 0; j < 16; j++) {
            float dA  = fmaxf(__expf(dtv * Acoef[j]), 1e-38f);
            float dbx = fmaxf(dtv * bcB[i][j] * xv, 1e-38f);
            h[j] = fmaf(dA, h[j], dbx);
            p[j] *= dA;
        }
    }

    size_t base = soff + (size_t)((b * nchunk + chunk) * 16) * 1024 + d;
#pragma unroll
    for (int j = 0; j < 16; j++) {
        prodA_buf[base + (size_t)j * 1024] = p[j];
        h_buf[base + (size_t)j * 1024] = h[j];
    }
}

__global__ __launch_bounds__(256) void scan_pass2(
    const float* __restrict__ dt0, const float* __restrict__ xc0,
    const float* __restrict__ pj0, float* __restrict__ y0,
    const float* __restrict__ dt1, const float* __restrict__ xc1,
    const float* __restrict__ pj1, float* __restrict__ y1,
    const float* __restrict__ dt2, const float* __restrict__ xc2,
    const float* __restrict__ pj2, float* __restrict__ y2,
    const float* __restrict__ A_log, const float* __restrict__ D_p,
    const float* __restrict__ prodA_buf, const float* __restrict__ h_buf)
{
    int s, nchunk, Ts, dquad, chunk, b; size_t soff;
    scan_decode(blockIdx.x, s, nchunk, Ts, dquad, chunk, b, soff);
    const float* dt = (s == 0) ? dt0 : (s == 1) ? dt1 : dt2;
    const float* xc = (s == 0) ? xc0 : (s == 1) ? xc1 : xc2;
    const float* pj = (s == 0) ? pj0 : (s == 1) ? pj1 : pj2;
    float* y        = (s == 0) ? y0  : (s == 1) ? y1  : y2;

    const int d = dquad * 256 + threadIdx.x;
    const size_t rowbase = (size_t)b * Ts;
    const int t0 = chunk * CHUNK;

    float Acoef[16], h[16];
#pragma unroll
    for (int j = 0; j < 16; j++) {
        Acoef[j] = -__expf(A_log[((size_t)(s * DINNER + d)) * 16 + j]);
        h[j] = 0.f;
    }
    const float Dp = D_p[s * DINNER + d];

    // carry-in: fold predecessor chunk states (coalesced, L2-resident)
    for (int c = 0; c < chunk; c++) {
        size_t cb = soff + (size_t)((b * nchunk + c) * 16) * 1024 + d;
#pragma unroll
        for (int j = 0; j < 16; j++)
            h[j] = fmaf(prodA_buf[cb + (size_t)j * 1024], h[j], h_buf[cb + (size_t)j * 1024]);
    }

    __shared__ float bc[CHUNK][32];   // B cols 0..15, C cols 16..31
    for (int u = threadIdx.x; u < CHUNK * 32; u += 256) {
        int i = u >> 5, jj = u & 31;
        bc[i][jj] = pj[(rowbase + t0 + i) * 96 + 64 + jj];
    }
    __syncthreads();

    for (int i = 0; i < CHUNK; i++) {
        size_t t = rowbase + t0 + i;
        float dtv = dt[t * DINNER + d];
        float xv  = xc[t * DINNER + d];
        float accy = 0.f;
#pragma unroll
        for (int j = 0; j < 16; j++) {
            float dA  = fmaxf(__expf(dtv * Acoef[j]), 1e-38f);
            float dbx = fmaxf(dtv * bc[i][j] * xv, 1e-38f);
            h[j] = fmaf(dA, h[j], dbx);
            accy = fmaf(bc[i][16 + j], h[j], accy);
        }
        y[t * DINNER + d] = accy + Dp * xv;
    }
}

// ---------------------------------------------------------------------------
__global__ void fuse_kernel(const float* __restrict__ y0, const float* __restrict__ y1,
                            const float* __restrict__ y2, const float* __restrict__ sw,
                            float* __restrict__ fused, float* __restrict__ ctx)
{
    int idx = blockIdx.x * blockDim.x + threadIdx.x;
    if (idx >= BATCH * SEQ * DINNER) return;
    int d = idx & (DINNER - 1);
    int t = (idx >> 10) & (SEQ - 1);
    int b = idx >> 20;
    float v0 = y0[idx];
    float v1 = y1[((size_t)(b * 512) + (t >> 1)) * DINNER + d];
    float v2 = y2[((size_t)(b * 256) + (t >> 2)) * DINNER + d];
    float s0 = sw[0], s1 = sw[1], s2 = sw[2];
    float mx = fmaxf(s0, fmaxf(s1, s2));
    float e0 = __expf(s0 - mx), e1 = __expf(s1 - mx), e2 = __expf(s2 - mx);
    float inv = 1.f / (e0 + e1 + e2);
    fused[idx] = (e0 * v0 + e1 * v1 + e2 * v2) * inv;
    ctx[idx] = (v0 + v1 + v2) * (1.f / 3.f);
}

__global__ void gate_mul_kernel(float* __restrict__ fused, const float* __restrict__ cg,
                                const float* __restrict__ xz)
{
    int idx = blockIdx.x * blockDim.x + threadIdx.x;
    if (idx >= BATCH * SEQ * DINNER) return;
    int token = idx >> 10;
    int d = idx & (DINNER - 1);
    float g = xz[(size_t)token * 2048 + 1024 + d];
    fused[idx] = fused[idx] * cg[idx] * siluf_(g);
}

__global__ __launch_bounds__(256) void ln_kernel(
    const float* __restrict__ yin, const float* __restrict__ gamma,
    const float* __restrict__ beta, float* __restrict__ out)
{
    int token = blockIdx.x;
    int tid = threadIdx.x;
    const float* row = yin + (size_t)token * DIMSZ;
    float v0 = row[tid], v1 = row[tid + 256];
    __shared__ float s1[256], s2[256];
    s1[tid] = v0 + v1;
    s2[tid] = v0 * v0 + v1 * v1;
    __syncthreads();
    for (int off = 128; off > 0; off >>= 1) {
        if (tid < off) { s1[tid] += s1[tid + off]; s2[tid] += s2[tid + off]; }
        __syncthreads();
    }
    float mu = s1[0] * (1.f / 512.f);
    float var = s2[0] * (1.f / 512.f) - mu * mu;
    float rstd = rsqrtf(var + 1e-5f);
    float* orow = out + (size_t)token * DIMSZ;
    orow[tid]       = (v0 - mu) * rstd * gamma[tid]       + beta[tid];
    orow[tid + 256] = (v1 - mu) * rstd * gamma[tid + 256] + beta[tid + 256];
}

// ---------------------------------------------------------------------------
extern "C" void kernel_launch(void* const* d_in, const int* in_sizes, int n_in,
                              void* d_out, int out_size, void* d_ws, size_t ws_size,
                              hipStream_t stream)
{
    const float* x         = (const float*)d_in[0];
    const float* in_proj_w = (const float*)d_in[1];
    const float* conv_w    = (const float*)d_in[2];
    const float* conv_b    = (const float*)d_in[3];
    const float* xproj_w   = (const float*)d_in[4];
    const float* dtproj_w  = (const float*)d_in[5];
    const float* dtproj_b  = (const float*)d_in[6];
    const float* A_log     = (const float*)d_in[7];
    const float* D_p       = (const float*)d_in[8];
    const float* scale_w   = (const float*)d_in[9];
    const float* cg_w1     = (const float*)d_in[10];
    const float* cg_w2     = (const float*)d_in[11];
    const float* out_pw    = (const float*)d_in[12];
    const float* ln_gamma  = (const float*)d_in[13];
    const float* ln_beta   = (const float*)d_in[14];
    float* out = (float*)d_out;

    float* ws = (float*)d_ws;
    float* xz    = ws;                       // 2048 x 2048
    float* xs1   = xz    + 4194304;          // 1024 x 1024
    float* xs2   = xs1   + 1048576;          // 512  x 1024
    float* xc0   = xs2   + 524288;           // 2048 x 1024
    float* xc1   = xc0   + 2097152;          // 1024 x 1024
    float* xc2   = xc1   + 1048576;          // 512  x 1024
    float* pj0   = xc2   + 524288;           // 2048 x 96
    float* pj1   = pj0   + 196608;           // 1024 x 96
    float* pj2   = pj1   + 98304;            // 512  x 96
    float* dt0   = pj2   + 49152;            // 2048 x 1024
    float* dt1   = dt0   + 2097152;          // 1024 x 1024
    float* dt2   = dt1   + 1048576;          // 512  x 1024
    float* y0    = dt2   + 524288;           // 2048 x 1024
    float* y1    = y0    + 2097152;          // 1024 x 1024
    float* y2    = y1    + 1048576;          // 512  x 1024
    float* prodA = y2    + 524288;           // 1,835,008 (chunk states)
    float* hbuf  = prodA + 1835008;          // 1,835,008
    // overlays (dead after scan):
    float* fused = dt0;                      // 2048 x 1024
    float* ctx   = xc0;                      // 2048 x 1024 (then cg out)
    float* h1cg  = dt1;                      // 2048 x 512
    float* outpre= xc1;                      // 2048 x 512
    // ws total: ~20.8M floats = 83 MB

    const int M0 = BATCH * SEQ;   // 2048
    const int M1 = BATCH * 512;
    const int M2 = BATCH * 256;

    // 1) in_proj
    gemm_kernel<0, false, false><<<dim3(M0 / 64, 2048 / 64), 256, 0, stream>>>(
        x, DIMSZ, in_proj_w, nullptr, nullptr, xz, 2048, M0, 2048, DIMSZ);

    // 2) downsample
    downsample_kernel<<<(BATCH * 512 * DINNER) / 256, 256, 0, stream>>>(xz, 2048, 512, 2, xs1);
    downsample_kernel<<<(BATCH * 256 * DINNER) / 256, 256, 0, stream>>>(xz, 2048, 256, 4, xs2);

    // 3) conv + SiLU
    conv_silu_kernel<<<(BATCH * 1024 * DINNER) / 256, 256, 0, stream>>>(
        xz, 2048, 1024, conv_w + 0 * 4096, conv_b + 0 * DINNER, xc0);
    conv_silu_kernel<<<(BATCH * 512 * DINNER) / 256, 256, 0, stream>>>(
        xs1, 1024, 512, conv_w + 1 * 4096, conv_b + 1 * DINNER, xc1);
    conv_silu_kernel<<<(BATCH * 256 * DINNER) / 256, 256, 0, stream>>>(
        xs2, 1024, 256, conv_w + 2 * 4096, conv_b + 2 * DINNER, xc2);

    // 4) xproj
    gemm_kernel<0, false, false><<<dim3(M0 / 64, 2), 256, 0, stream>>>(
        xc0, DINNER, xproj_w + 0 * 96 * DINNER, nullptr, nullptr, pj0, 96, M0, 96, DINNER);
    gemm_kernel<0, false, false><<<dim3(M1 / 64, 2), 256, 0, stream>>>(
        xc1, DINNER, xproj_w + 1 * 96 * DINNER, nullptr, nullptr, pj1, 96, M1, 96, DINNER);
    gemm_kernel<0, false, false><<<dim3(M2 / 64, 2), 256, 0, stream>>>(
        xc2, DINNER, xproj_w + 2 * 96 * DINNER, nullptr, nullptr, pj2, 96, M2, 96, DINNER);

    // 5) dtproj + softplus
    gemm_kernel<3, true, false><<<dim3(M0 / 64, 16), 256, 0, stream>>>(
        pj0, 96, dtproj_w + 0 * DINNER * DTRANK, dtproj_b + 0 * DINNER, nullptr,
        dt0, DINNER, M0, DINNER, DTRANK);
    gemm_kernel<3, true, false><<<dim3(M1 / 64, 16), 256, 0, stream>>>(
        pj1, 96, dtproj_w + 1 * DINNER * DTRANK, dtproj_b + 1 * DINNER, nullptr,
        dt1, DINNER, M1, DINNER, DTRANK);
    gemm_kernel<3, true, false><<<dim3(M2 / 64, 16), 256, 0, stream>>>(
        pj2, 96, dtproj_w + 2 * DINNER * DTRANK, dtproj_b + 2 * DINNER, nullptr,
        dt2, DINNER, M2, DINNER, DTRANK);

    // 6) chunked selective scan (2 passes, 448 blocks each)
    scan_pass1<<<448, 256, 0, stream>>>(dt0, xc0, pj0, dt1, xc1, pj1,
                                        dt2, xc2, pj2, A_log, prodA, hbuf);
    scan_pass2<<<448, 256, 0, stream>>>(dt0, xc0, pj0, y0, dt1, xc1, pj1, y1,
                                        dt2, xc2, pj2, y2, A_log, D_p, prodA, hbuf);

    // 7) fuse + ctx
    fuse_kernel<<<(BATCH * SEQ * DINNER) / 256, 256, 0, stream>>>(y0, y1, y2, scale_w, fused, ctx);

    // 8) cg1
    gemm_kernel<1, false, false><<<dim3(M0 / 64, 8), 256, 0, stream>>>(
        ctx, DINNER, cg_w1, nullptr, nullptr, h1cg, 512, M0, 512, DINNER);

    // 9) cg2
    gemm_kernel<2, false, false><<<dim3(M0 / 64, 16), 256, 0, stream>>>(
        h1cg, 512, cg_w2, nullptr, nullptr, ctx, DINNER, M0, DINNER, 512);

    // 10) gate
    gate_mul_kernel<<<(BATCH * SEQ * DINNER) / 256, 256, 0, stream>>>(fused, ctx, xz);

    // 11) out_proj + residual
    gemm_kernel<0, false, true><<<dim3(M0 / 64, 8), 256, 0, stream>>>(
        fused, DINNER, out_pw, nullptr, x, outpre, DIMSZ, M0, DIMSZ, DINNER);

    // 12) LayerNorm
    ln_kernel<<<M0, 256, 0, stream>>>(outpre, ln_gamma, ln_beta, out);
}